// Round 9
// baseline (477.652 us; speedup 1.0000x reference)
//
#include <hip/hip_runtime.h>
#include <hip/hip_fp16.h>

#define N_NODES   100000
#define N_EDGES   3200000
#define N_FEAT    128
#define HIDDEN    16
#define N_CLASSES 10
#define N_GRAPHS  512
#define SLOT      80                       // csr words per node (320B = 5 lines; P(deg>=80) ~ 5e-13)

// ---------------- CSR via per-node atomic cursors (no partition stage) ----------------

__global__ void cursor_init_kernel(int* __restrict__ cursor) {
    int v = blockIdx.x * 256 + threadIdx.x;
    if (v < N_NODES) cursor[v] = v * SLOT;
}

// one thread = 2 edges: slot = atomicAdd(cursor[dst]); csr[slot] = src
// (device-scope atomics; cursors L2-resident, ~deg collisions per cursor)
__global__ void scatter_kernel(const int* __restrict__ src, const int* __restrict__ dst,
                               int* __restrict__ cursor, int* __restrict__ csr) {
    int t = blockIdx.x * 256 + threadIdx.x;      // 6250*256 = 1.6M exact
    int2 s2 = ((const int2*)src)[t];
    int2 d2 = ((const int2*)dst)[t];
    int slot0 = atomicAdd(&cursor[d2.x], 1);
    csr[slot0] = s2.x;
    int slot1 = atomicAdd(&cursor[d2.y], 1);
    csr[slot1] = s2.y;
}

// ---------------- layer kernels (g stored fp16: row = 16 halves = 32B) ----------------

__device__ __forceinline__ void pack_store8(__half* outp, int idx, const float* o) {
    int4 w;
    __half2 q;
    q = __floats2half2_rn(o[0], o[1]); w.x = *(int*)&q;
    q = __floats2half2_rn(o[2], o[3]); w.y = *(int*)&q;
    q = __floats2half2_rn(o[4], o[5]); w.z = *(int*)&q;
    q = __floats2half2_rn(o[6], o[7]); w.w = *(int*)&q;
    ((int4*)outp)[idx] = w;
}

// g[v] = dinv[v] * (x[v] @ W1);  dinv computed inline from cursor (deg = cur - v*SLOT)
// 4 lanes per row; lane q reads float4s k4 = q, q+4, ... so each wave load instr
// consumes 16 rows x 64B fully-contiguous chunks (no HBM over-fetch). W packed once
// per block into LDS as fp16 (k-pair, f) half2 tiles, broadcast ds_read_b128;
// __hfma2 dual fp16 accumulate; quad-reduce via 2 shfl_xor.
__global__ __launch_bounds__(256) void transform_x_kernel(const float* __restrict__ x,
                                                          const float* __restrict__ W,
                                                          const int* __restrict__ cursor,
                                                          __half* __restrict__ g) {
    __shared__ __half2 Wp[1024];   // [kp=64][f=16]: (W[2kp][f], W[2kp+1][f])
    int tid = threadIdx.x;
    for (int i = tid; i < 1024; i += 256) {
        int kp = i >> 4, f = i & 15;
        Wp[i] = __floats2half2_rn(W[(2 * kp) * HIDDEN + f], W[(2 * kp + 1) * HIDDEN + f]);
    }
    __syncthreads();
    int l  = tid & 63;
    int wv = tid >> 6;
    int rw = l >> 2;          // row within wave: 0..15
    int q  = l & 3;           // k4 phase
    int row = blockIdx.x * 64 + wv * 16 + rw;
    if (row >= N_NODES) return;   // whole quad (and whole wave) exits together
    const float4* xp = (const float4*)x + (size_t)row * 32;
    float4 xr[8];
#pragma unroll
    for (int s8 = 0; s8 < 8; ++s8) xr[s8] = xp[q + 4 * s8];   // 64B/lane-quad contiguous
    __half2 acc[16];
    const __half2 z2 = __floats2half2_rn(0.f, 0.f);
#pragma unroll
    for (int f = 0; f < 16; ++f) acc[f] = z2;
    const int4* w4 = (const int4*)Wp;
#pragma unroll
    for (int s8 = 0; s8 < 8; ++s8) {
        int k4 = q + 4 * s8;
        __half2 xp0 = __floats2half2_rn(xr[s8].x, xr[s8].y);
        __half2 xp1 = __floats2half2_rn(xr[s8].z, xr[s8].w);
#pragma unroll
        for (int hf = 0; hf < 2; ++hf) {
            int kp = 2 * k4 + hf;
            __half2 xv = hf ? xp1 : xp0;
#pragma unroll
            for (int j = 0; j < 4; ++j) {
                int4 wj = w4[kp * 4 + j];                // uniform addr -> broadcast
                const __half2* wvv = (const __half2*)&wj;
#pragma unroll
                for (int ff = 0; ff < 4; ++ff)
                    acc[j * 4 + ff] = __hfma2(xv, wvv[ff], acc[j * 4 + ff]);
            }
        }
    }
    int deg = cursor[row] - row * SLOT;
    float di = rsqrtf((float)(deg + 1));                 // +1 self-loop
    float o[16];
#pragma unroll
    for (int f = 0; f < 16; ++f) {
        float2 t = __half22float2(acc[f]);
        float sv = t.x + t.y;
        sv += __shfl_xor(sv, 1);
        sv += __shfl_xor(sv, 2);
        o[f] = sv * di;
    }
    if (q == 0) {
        pack_store8(g, row * 2,     &o[0]);
        pack_store8(g, row * 2 + 1, &o[8]);
    }
}

// aggregate + optional fused next-layer transform.
// MODE 0: out[v] = agg + bias                       (no relu; feeds pooling)
// MODE 2: out[v] = dinv[v] * (relu(agg + bias) @ Wn)  (g for next layer)
// beg = v*SLOT (line-aligned), end = cursor[v], dinv inline from deg = end-beg.
// lane layout: lane = c*8 + vl*2 + hh  (c: edge slot 0..7, vl: node 0..3, hh: feat half)
// grid is exactly N_NODES/16 blocks -> no v bound check needed (100000 = 6250*16)
template <int MODE>
__global__ __launch_bounds__(256) void aggregate_kernel(
        const __half* __restrict__ g, const int* __restrict__ cursor,
        const int* __restrict__ csr,
        const float* __restrict__ bias, const float* __restrict__ Wn,
        __half* __restrict__ out) {
    __shared__ float WnL[HIDDEN * HIDDEN];
    int tid  = threadIdx.x;
    int wave = tid >> 6;
    int l    = tid & 63;
    int c  = l >> 3;
    int vl = (l >> 1) & 3;
    int hh = l & 1;
    int v = blockIdx.x * 16 + wave * 4 + vl;
    int end = cursor[v];                     // issued before the LDS staging barrier
    if (MODE == 2) {
        if (tid < HIDDEN * HIDDEN) WnL[tid] = Wn[tid];
        __syncthreads();
    }
    int beg = v * SLOT;
    const int4* g4 = (const int4*)g;
    float a0 = 0.f, a1 = 0.f, a2 = 0.f, a3 = 0.f, a4 = 0.f, a5 = 0.f, a6 = 0.f, a7 = 0.f;
    // interleaved (stride-8) edge assignment: lanes c=0..7 of a node-half read
    // 8 CONSECUTIVE csr words per iteration -> coalesced 32B runs
#pragma unroll 4
    for (int j = beg + c; j < end; j += 8) {
        int s = csr[j];
        int4 r = g4[s * 2 + hh];
        float2 f0 = __half22float2(*(const __half2*)&r.x);
        float2 f1 = __half22float2(*(const __half2*)&r.y);
        float2 f2 = __half22float2(*(const __half2*)&r.z);
        float2 f3 = __half22float2(*(const __half2*)&r.w);
        a0 += f0.x; a1 += f0.y; a2 += f1.x; a3 += f1.y;
        a4 += f2.x; a5 += f2.y; a6 += f3.x; a7 += f3.y;
    }
    // combine the 8 edge-slot partials (lanes differing in bits 3,4,5)
    a0 += __shfl_xor(a0, 8);  a1 += __shfl_xor(a1, 8);
    a2 += __shfl_xor(a2, 8);  a3 += __shfl_xor(a3, 8);
    a4 += __shfl_xor(a4, 8);  a5 += __shfl_xor(a5, 8);
    a6 += __shfl_xor(a6, 8);  a7 += __shfl_xor(a7, 8);
    a0 += __shfl_xor(a0, 16); a1 += __shfl_xor(a1, 16);
    a2 += __shfl_xor(a2, 16); a3 += __shfl_xor(a3, 16);
    a4 += __shfl_xor(a4, 16); a5 += __shfl_xor(a5, 16);
    a6 += __shfl_xor(a6, 16); a7 += __shfl_xor(a7, 16);
    a0 += __shfl_xor(a0, 32); a1 += __shfl_xor(a1, 32);
    a2 += __shfl_xor(a2, 32); a3 += __shfl_xor(a3, 32);
    a4 += __shfl_xor(a4, 32); a5 += __shfl_xor(a5, 32);
    a6 += __shfl_xor(a6, 32); a7 += __shfl_xor(a7, 32);
    if (c == 0) {
        int4 r = g4[v * 2 + hh];  // self-loop contribution
        float2 s0 = __half22float2(*(const __half2*)&r.x);
        float2 s1 = __half22float2(*(const __half2*)&r.y);
        float2 s2 = __half22float2(*(const __half2*)&r.z);
        float2 s3 = __half22float2(*(const __half2*)&r.w);
        float di = rsqrtf((float)(end - beg + 1));   // dinv inline (+1 self-loop)
        const float4* bp = (const float4*)bias;
        float4 bA = bp[hh * 2];
        float4 bB = bp[hh * 2 + 1];
        float o[8];
        o[0] = di * (a0 + s0.x) + bA.x;
        o[1] = di * (a1 + s0.y) + bA.y;
        o[2] = di * (a2 + s1.x) + bA.z;
        o[3] = di * (a3 + s1.y) + bA.w;
        o[4] = di * (a4 + s2.x) + bB.x;
        o[5] = di * (a5 + s2.y) + bB.y;
        o[6] = di * (a6 + s3.x) + bB.z;
        o[7] = di * (a7 + s3.y) + bB.w;
        if (MODE == 2) {
            // relu, then fused 16x16 transform: this lane holds h feats
            // [hh*8, hh*8+8); partial dot against all 16 outputs, then swap
            // cross-half partials with the hh-partner lane (xor 1).
#pragma unroll
            for (int i = 0; i < 8; ++i) o[i] = fmaxf(o[i], 0.f);
            float pa[16];
#pragma unroll
            for (int f = 0; f < 16; ++f) pa[f] = 0.f;
            const float* wr = &WnL[hh * 8 * HIDDEN];
#pragma unroll
            for (int qq = 0; qq < 8; ++qq) {
                float hq = o[qq];
#pragma unroll
                for (int f = 0; f < 16; ++f) pa[f] += hq * wr[qq * HIDDEN + f];
            }
            float o2[8];
#pragma unroll
            for (int i = 0; i < 8; ++i) {
                float lo = pa[i];       // partials for f = i
                float hi = pa[8 + i];   // partials for f = 8 + i
                float keep = hh ? hi : lo;   // own output range
                float send = hh ? lo : hi;   // partner's output range
                float recv = __shfl_xor(send, 1);
                o2[i] = di * (keep + recv);
            }
            pack_store8(out, v * 2 + hh, o2);
        } else {
            pack_store8(out, v * 2 + hh, o);
        }
    }
}

// ---------------- fused pooling + head (batch is sorted -> contiguous graph ranges) ----------------

__global__ void pool_head_kernel(const __half* __restrict__ h, const int* __restrict__ batch,
                                 const float* __restrict__ Wlin, const float* __restrict__ blin,
                                 float* __restrict__ out) {
    __shared__ float red[256];
    __shared__ int bounds[2];
    int g   = blockIdx.x;
    int tid = threadIdx.x;
    if (tid < 2) {
        int target = g + tid;   // lower_bound(batch, target)
        int lo = 0, hi = N_NODES;
        while (lo < hi) {
            int mid = (lo + hi) >> 1;
            if (batch[mid] < target) lo = mid + 1; else hi = mid;
        }
        bounds[tid] = lo;
    }
    __syncthreads();
    int start = bounds[0], end = bounds[1];
    int f = tid & 15, r = tid >> 4;
    float acc = 0.f;
    for (int v = start + r; v < end; v += 16)
        acc += __half2float(h[v * HIDDEN + f]);
    red[tid] = acc;
    __syncthreads();
    for (int off = 128; off >= 16; off >>= 1) {
        if (tid < off) red[tid] += red[tid + off];
        __syncthreads();
    }
    if (tid < N_CLASSES) {
        float s = blin[tid];
#pragma unroll
        for (int fe = 0; fe < HIDDEN; ++fe) s += red[fe] * Wlin[fe * N_CLASSES + tid];
        out[g * N_CLASSES + tid] = s;
    }
}

// ---------------- launch ----------------

extern "C" void kernel_launch(void* const* d_in, const int* in_sizes, int n_in,
                              void* d_out, int out_size, void* d_ws, size_t ws_size,
                              hipStream_t stream) {
    const float* x     = (const float*)d_in[0];
    const int*   ei    = (const int*)d_in[1];
    const int*   src   = ei;
    const int*   dst   = ei + N_EDGES;
    const int*   batch = (const int*)d_in[2];
    const float* W1 = (const float*)d_in[3];
    const float* b1 = (const float*)d_in[4];
    const float* W2 = (const float*)d_in[5];
    const float* b2 = (const float*)d_in[6];
    const float* W3 = (const float*)d_in[7];
    const float* b3 = (const float*)d_in[8];
    const float* Wlin = (const float*)d_in[9];
    const float* blin = (const float*)d_in[10];
    float* out = (float*)d_out;

    char* w = (char*)d_ws;
    auto alloc = [&](size_t bytes) -> char* {
        char* p = w;
        w += (bytes + 255) & ~(size_t)255;
        return p;
    };
    int*    cursor = (int*)alloc((size_t)N_NODES * 4);
    __half* gA     = (__half*)alloc((size_t)N_NODES * HIDDEN * 2);
    __half* gB     = (__half*)alloc((size_t)N_NODES * HIDDEN * 2);
    __half* hA     = (__half*)alloc((size_t)N_NODES * HIDDEN * 2);
    int*    csr    = (int*)alloc((size_t)N_NODES * SLOT * 4 + 256);   // 32 MB (+ overflow pad)

    int nbn = (N_NODES + 255) / 256;        // 391
    int ntx = (N_NODES + 63) / 64;          // 1563 (64 rows per block)
    int nsc = (N_EDGES / 2 + 255) / 256;    // 6250 (exact: 6250*256*2 == N_EDGES)
    int ab  = (N_NODES + 15) / 16;          // 6250 (exact: 6250*16 == 100000)

    cursor_init_kernel<<<nbn, 256, 0, stream>>>(cursor);
    scatter_kernel<<<nsc, 256, 0, stream>>>(src, dst, cursor, csr);

    // layer 1 transform (dinv inline from cursor)
    transform_x_kernel<<<ntx, 256, 0, stream>>>(x, W1, cursor, gA);
    // layer 1 aggregate + fused layer-2 transform
    aggregate_kernel<2><<<ab, 256, 0, stream>>>(gA, cursor, csr, b1, W2, gB);
    // layer 2 aggregate + fused layer-3 transform
    aggregate_kernel<2><<<ab, 256, 0, stream>>>(gB, cursor, csr, b2, W3, gA);
    // layer 3 aggregate (no relu, plain h out)
    aggregate_kernel<0><<<ab, 256, 0, stream>>>(gA, cursor, csr, b3, nullptr, hA);

    pool_head_kernel<<<N_GRAPHS, 256, 0, stream>>>(hA, batch, Wlin, blin, out);
}

// Round 11
// 303.656 us; speedup vs baseline: 1.5730x; 1.5730x over previous
//
#include <hip/hip_runtime.h>
#include <hip/hip_fp16.h>

#define N_NODES   100000
#define N_EDGES   3200000
#define N_FEAT    128
#define HIDDEN    16
#define N_CLASSES 10
#define N_GRAPHS  512
#define NPB       256                      // dst nodes per bucket
#define NBUCKET   391                      // ceil(N_NODES / NPB)
#define EPB       4096                     // edges per partition block
#define PBLK      ((N_EDGES + EPB - 1) / EPB)   // 782
#define PSLACK    15872                    // part stride/bucket (words); 16-aligned
#define CSLACK    9216                     // csr stride/bucket: mean 8184 + 11 sigma

typedef float vf4 __attribute__((ext_vector_type(4)));   // nontemporal-compatible 16B vector

// ---------------- partition: LDS counting sort + line-aligned flush ----------------
// cur[b] holds the bucket's allocation OFFSET (memset to 0 each replay).
// record: src | (dst&255)<<17 ; sentinel 0xFFFFFFFF fills 64B-alignment padding.
// All pure streams (src/dst/part) use non-temporal ops so they don't pollute L2.

__global__ __launch_bounds__(512) void partition_kernel(const int* __restrict__ src,
                                                        const int* __restrict__ dst,
                                                        int* __restrict__ cur,
                                                        unsigned* __restrict__ part) {
    __shared__ int cnt[NBUCKET];
    __shared__ int lbase[NBUCKET];
    __shared__ int rk[NBUCKET];
    __shared__ int gbase[NBUCKET];
    __shared__ int s[512];
    __shared__ unsigned sorted[EPB];
    __shared__ unsigned short bb[EPB];     // bucket id per edge
    __shared__ unsigned char  dl[EPB];     // dst & 255 per edge
    int tid = threadIdx.x;
    for (int i = tid; i < NBUCKET; i += 512) cnt[i] = 0;
    __syncthreads();
    int s0 = blockIdx.x * EPB;
#pragma unroll
    for (int i = 0; i < EPB / 512; ++i) {
        int le = i * 512 + tid;
        int e  = s0 + le;
        if (e < N_EDGES) {
            int d = __builtin_nontemporal_load(&dst[e]);
            int b = d >> 8;
            bb[le] = (unsigned short)b;
            dl[le] = (unsigned char)(d & 255);
            atomicAdd(&cnt[b], 1);
        }
    }
    __syncthreads();
    int v = (tid < NBUCKET) ? cnt[tid] : 0;
    s[tid] = v;
    __syncthreads();
    for (int off = 1; off < 512; off <<= 1) {
        int t = (tid >= off) ? s[tid - off] : 0;
        __syncthreads();
        s[tid] += t;
        __syncthreads();
    }
    if (tid < NBUCKET) {
        int lb = s[tid] - v;
        lbase[tid] = lb;
        rk[tid]    = lb;
        int cpad = (v + 15) & ~15;                 // 64B-aligned reservation
        gbase[tid] = tid * PSLACK + (cpad ? atomicAdd(&cur[tid], cpad) : 0);
    }
    __syncthreads();
    // pass 2: stream src only; bucket/lowbyte from LDS; rank-scatter into LDS
#pragma unroll
    for (int i = 0; i < EPB / 512; ++i) {
        int le = i * 512 + tid;
        int e  = s0 + le;
        if (e < N_EDGES) {
            int b = bb[le];
            int r = atomicAdd(&rk[b], 1);
            sorted[r] = (unsigned)__builtin_nontemporal_load(&src[e]) | ((unsigned)dl[le] << 17);
        }
    }
    __syncthreads();
    // flush: 16-lane groups, contiguous 64B-aligned fully-written lines (nt stores)
    int w16 = tid >> 4, l16 = tid & 15;
    for (int b = w16; b < NBUCKET; b += 32) {
        int c = cnt[b];
        if (!c) continue;
        int cpad = (c + 15) & ~15;
        int lb = lbase[b], gb = gbase[b];
        for (int j = l16; j < cpad; j += 16)
            __builtin_nontemporal_store((j < c) ? sorted[lb + j] : 0xFFFFFFFFu, &part[gb + j]);
    }
}

// one block per bucket (512 thr): count pass captures per-record rank (byte) so the
// fill pass is atomic-free. deg <= ~80 (Poisson 32 tail) << 256, byte rank safe.
// part reads are non-temporal (read-once stream); csr writes stay cached (read 3x next).
__global__ __launch_bounds__(512) void build_csr_kernel(const unsigned* __restrict__ part,
                                                        const int* __restrict__ cur,
                                                        int2* __restrict__ rp,
                                                        float* __restrict__ dinv, int* __restrict__ csr) {
    __shared__ int ncnt[256];
    __shared__ int s[512];
    __shared__ unsigned char rkb[PSLACK];   // rank per record
    int b   = blockIdx.x;
    int tid = threadIdx.x;
    int beg = b * PSLACK, end = beg + cur[b];
    if (tid < 256) ncnt[tid] = 0;
    __syncthreads();
    for (int j = beg + tid; j < end; j += 512) {
        unsigned r = __builtin_nontemporal_load(&part[j]);
        if (r != 0xFFFFFFFFu)
            rkb[j - beg] = (unsigned char)atomicAdd(&ncnt[(r >> 17) & 255], 1);
    }
    __syncthreads();
    int deg = (tid < 256) ? ncnt[tid] : 0;
    s[tid] = deg;
    __syncthreads();
    for (int off = 1; off < 512; off <<= 1) {
        int t = (tid >= off) ? s[tid - off] : 0;
        __syncthreads();
        s[tid] += t;
        __syncthreads();
    }
    int excl = s[tid] - deg;
    int cbeg = b * CSLACK;
    if (tid < 256) {
        int node = b * 256 + tid;
        if (node < N_NODES) {
            rp[node]   = make_int2(cbeg + excl, cbeg + excl + deg);
            dinv[node] = rsqrtf((float)(deg + 1));  // +1 self-loop
        }
    }
    __syncthreads();
    if (tid < 256) ncnt[tid] = cbeg + excl;   // absolute base per node
    __syncthreads();
    // atomic-free fill: slot = base[node] + cached rank
    for (int j = beg + tid; j < end; j += 512) {
        unsigned r = __builtin_nontemporal_load(&part[j]);
        if (r != 0xFFFFFFFFu)
            csr[ncnt[(r >> 17) & 255] + rkb[j - beg]] = (int)(r & 0x1FFFFu);
    }
}

// ---------------- layer kernels (g stored fp16: row = 16 halves = 32B) ----------------

__device__ __forceinline__ void pack_store8(__half* outp, int idx, const float* o) {
    int4 w;
    __half2 q;
    q = __floats2half2_rn(o[0], o[1]); w.x = *(int*)&q;
    q = __floats2half2_rn(o[2], o[3]); w.y = *(int*)&q;
    q = __floats2half2_rn(o[4], o[5]); w.z = *(int*)&q;
    q = __floats2half2_rn(o[6], o[7]); w.w = *(int*)&q;
    ((int4*)outp)[idx] = w;
}

// g[v] = dinv[v] * (x[v] @ W1)
// 4 lanes per row; lane q reads 16B vectors k4 = q, q+4, ... so each wave load instr
// consumes 16 rows x 64B fully-contiguous chunks. x reads are NON-TEMPORAL (51 MB
// read-once stream must not evict L2); loaded via ext_vector_type (builtin requires
// native vector, not HIP_vector_type). W packed once per block into LDS as fp16
// (k-pair, f) half2 tiles, broadcast ds_read_b128; __hfma2 dual fp16 accumulate;
// quad-reduce via 2 shfl_xor.
__global__ __launch_bounds__(256) void transform_x_kernel(const float* __restrict__ x,
                                                          const float* __restrict__ W,
                                                          const float* __restrict__ dinv,
                                                          __half* __restrict__ g) {
    __shared__ __half2 Wp[1024];   // [kp=64][f=16]: (W[2kp][f], W[2kp+1][f])
    int tid = threadIdx.x;
    for (int i = tid; i < 1024; i += 256) {
        int kp = i >> 4, f = i & 15;
        Wp[i] = __floats2half2_rn(W[(2 * kp) * HIDDEN + f], W[(2 * kp + 1) * HIDDEN + f]);
    }
    __syncthreads();
    int l  = tid & 63;
    int wv = tid >> 6;
    int rw = l >> 2;          // row within wave: 0..15
    int q  = l & 3;           // k4 phase
    int row = blockIdx.x * 64 + wv * 16 + rw;
    if (row >= N_NODES) return;   // whole quad (and whole wave) exits together
    const vf4* xp = (const vf4*)(x + (size_t)row * N_FEAT);
    vf4 xr[8];
#pragma unroll
    for (int s8 = 0; s8 < 8; ++s8) xr[s8] = __builtin_nontemporal_load(&xp[q + 4 * s8]);
    __half2 acc[16];
    const __half2 z2 = __floats2half2_rn(0.f, 0.f);
#pragma unroll
    for (int f = 0; f < 16; ++f) acc[f] = z2;
    const int4* w4 = (const int4*)Wp;
#pragma unroll
    for (int s8 = 0; s8 < 8; ++s8) {
        int k4 = q + 4 * s8;
        __half2 xp0 = __floats2half2_rn(xr[s8].x, xr[s8].y);
        __half2 xp1 = __floats2half2_rn(xr[s8].z, xr[s8].w);
#pragma unroll
        for (int hf = 0; hf < 2; ++hf) {
            int kp = 2 * k4 + hf;
            __half2 xv = hf ? xp1 : xp0;
#pragma unroll
            for (int j = 0; j < 4; ++j) {
                int4 wj = w4[kp * 4 + j];                // uniform addr -> broadcast
                const __half2* wvv = (const __half2*)&wj;
#pragma unroll
                for (int ff = 0; ff < 4; ++ff)
                    acc[j * 4 + ff] = __hfma2(xv, wvv[ff], acc[j * 4 + ff]);
            }
        }
    }
    float di = dinv[row];
    float o[16];
#pragma unroll
    for (int f = 0; f < 16; ++f) {
        float2 t = __half22float2(acc[f]);
        float sv = t.x + t.y;
        sv += __shfl_xor(sv, 1);
        sv += __shfl_xor(sv, 2);
        o[f] = sv * di;
    }
    if (q == 0) {
        pack_store8(g, row * 2,     &o[0]);
        pack_store8(g, row * 2 + 1, &o[8]);
    }
}

// aggregate + optional fused next-layer transform.
// MODE 0: out[v] = agg + bias                       (no relu; feeds pooling)
// MODE 2: out[v] = dinv[v] * (relu(agg + bias) @ Wn)  (g for next layer)
// csr reads are NON-TEMPORAL: the 12.8 MB csr stream must not evict the 3.2 MB
// L2-resident g table the random gathers depend on (R9 measured random-64B HBM
// at ~700 GB/s -- keeping g in L2 is the whole game).
// lane layout: lane = c*8 + vl*2 + hh  (c: edge slot 0..7, vl: node 0..3, hh: feat half)
template <int MODE>
__global__ __launch_bounds__(256) void aggregate_kernel(
        const __half* __restrict__ g, const int2* __restrict__ rp,
        const int* __restrict__ csr, const float* __restrict__ dinv,
        const float* __restrict__ bias, const float* __restrict__ Wn,
        __half* __restrict__ out) {
    __shared__ float WnL[HIDDEN * HIDDEN];
    int tid  = threadIdx.x;
    int wave = tid >> 6;
    int l    = tid & 63;
    int c  = l >> 3;
    int vl = (l >> 1) & 3;
    int hh = l & 1;
    int v = blockIdx.x * 16 + wave * 4 + vl;
    int2 range = rp[v];                      // issued before the LDS staging barrier
    if (MODE == 2) {
        if (tid < HIDDEN * HIDDEN) WnL[tid] = Wn[tid];
        __syncthreads();
    }
    int beg = range.x, end = range.y;
    const int4* g4 = (const int4*)g;
    float a0 = 0.f, a1 = 0.f, a2 = 0.f, a3 = 0.f, a4 = 0.f, a5 = 0.f, a6 = 0.f, a7 = 0.f;
    // interleaved (stride-8) edge assignment: lanes c=0..7 of a node-half read
    // 8 CONSECUTIVE csr words per iteration -> coalesced 32B runs
#pragma unroll 4
    for (int j = beg + c; j < end; j += 8) {
        int s = __builtin_nontemporal_load(&csr[j]);
        int4 r = g4[s * 2 + hh];
        float2 f0 = __half22float2(*(const __half2*)&r.x);
        float2 f1 = __half22float2(*(const __half2*)&r.y);
        float2 f2 = __half22float2(*(const __half2*)&r.z);
        float2 f3 = __half22float2(*(const __half2*)&r.w);
        a0 += f0.x; a1 += f0.y; a2 += f1.x; a3 += f1.y;
        a4 += f2.x; a5 += f2.y; a6 += f3.x; a7 += f3.y;
    }
    // combine the 8 edge-slot partials (lanes differing in bits 3,4,5)
    a0 += __shfl_xor(a0, 8);  a1 += __shfl_xor(a1, 8);
    a2 += __shfl_xor(a2, 8);  a3 += __shfl_xor(a3, 8);
    a4 += __shfl_xor(a4, 8);  a5 += __shfl_xor(a5, 8);
    a6 += __shfl_xor(a6, 8);  a7 += __shfl_xor(a7, 8);
    a0 += __shfl_xor(a0, 16); a1 += __shfl_xor(a1, 16);
    a2 += __shfl_xor(a2, 16); a3 += __shfl_xor(a3, 16);
    a4 += __shfl_xor(a4, 16); a5 += __shfl_xor(a5, 16);
    a6 += __shfl_xor(a6, 16); a7 += __shfl_xor(a7, 16);
    a0 += __shfl_xor(a0, 32); a1 += __shfl_xor(a1, 32);
    a2 += __shfl_xor(a2, 32); a3 += __shfl_xor(a3, 32);
    a4 += __shfl_xor(a4, 32); a5 += __shfl_xor(a5, 32);
    a6 += __shfl_xor(a6, 32); a7 += __shfl_xor(a7, 32);
    if (c == 0) {
        int4 r = g4[v * 2 + hh];  // self-loop contribution
        float2 s0 = __half22float2(*(const __half2*)&r.x);
        float2 s1 = __half22float2(*(const __half2*)&r.y);
        float2 s2 = __half22float2(*(const __half2*)&r.z);
        float2 s3 = __half22float2(*(const __half2*)&r.w);
        float di = dinv[v];
        const float4* bp = (const float4*)bias;
        float4 bA = bp[hh * 2];
        float4 bB = bp[hh * 2 + 1];
        float o[8];
        o[0] = di * (a0 + s0.x) + bA.x;
        o[1] = di * (a1 + s0.y) + bA.y;
        o[2] = di * (a2 + s1.x) + bA.z;
        o[3] = di * (a3 + s1.y) + bA.w;
        o[4] = di * (a4 + s2.x) + bB.x;
        o[5] = di * (a5 + s2.y) + bB.y;
        o[6] = di * (a6 + s3.x) + bB.z;
        o[7] = di * (a7 + s3.y) + bB.w;
        if (MODE == 2) {
            // relu, then fused 16x16 transform: this lane holds h feats
            // [hh*8, hh*8+8); partial dot against all 16 outputs, then swap
            // cross-half partials with the hh-partner lane (xor 1).
#pragma unroll
            for (int i = 0; i < 8; ++i) o[i] = fmaxf(o[i], 0.f);
            float pa[16];
#pragma unroll
            for (int f = 0; f < 16; ++f) pa[f] = 0.f;
            const float* wr = &WnL[hh * 8 * HIDDEN];
#pragma unroll
            for (int qq = 0; qq < 8; ++qq) {
                float hq = o[qq];
#pragma unroll
                for (int f = 0; f < 16; ++f) pa[f] += hq * wr[qq * HIDDEN + f];
            }
            float o2[8];
#pragma unroll
            for (int i = 0; i < 8; ++i) {
                float lo = pa[i];       // partials for f = i
                float hi = pa[8 + i];   // partials for f = 8 + i
                float keep = hh ? hi : lo;   // own output range
                float send = hh ? lo : hi;   // partner's output range
                float recv = __shfl_xor(send, 1);
                o2[i] = di * (keep + recv);
            }
            pack_store8(out, v * 2 + hh, o2);
        } else {
            pack_store8(out, v * 2 + hh, o);
        }
    }
}

// ---------------- fused pooling + head (batch is sorted -> contiguous graph ranges) ----------------

__global__ void pool_head_kernel(const __half* __restrict__ h, const int* __restrict__ batch,
                                 const float* __restrict__ Wlin, const float* __restrict__ blin,
                                 float* __restrict__ out) {
    __shared__ float red[256];
    __shared__ int bounds[2];
    int g   = blockIdx.x;
    int tid = threadIdx.x;
    if (tid < 2) {
        int target = g + tid;   // lower_bound(batch, target)
        int lo = 0, hi = N_NODES;
        while (lo < hi) {
            int mid = (lo + hi) >> 1;
            if (batch[mid] < target) lo = mid + 1; else hi = mid;
        }
        bounds[tid] = lo;
    }
    __syncthreads();
    int start = bounds[0], end = bounds[1];
    int f = tid & 15, r = tid >> 4;
    float acc = 0.f;
    for (int v = start + r; v < end; v += 16)
        acc += __half2float(h[v * HIDDEN + f]);
    red[tid] = acc;
    __syncthreads();
    for (int off = 128; off >= 16; off >>= 1) {
        if (tid < off) red[tid] += red[tid + off];
        __syncthreads();
    }
    if (tid < N_CLASSES) {
        float s = blin[tid];
#pragma unroll
        for (int fe = 0; fe < HIDDEN; ++fe) s += red[fe] * Wlin[fe * N_CLASSES + tid];
        out[g * N_CLASSES + tid] = s;
    }
}

// ---------------- launch ----------------

extern "C" void kernel_launch(void* const* d_in, const int* in_sizes, int n_in,
                              void* d_out, int out_size, void* d_ws, size_t ws_size,
                              hipStream_t stream) {
    const float* x     = (const float*)d_in[0];
    const int*   ei    = (const int*)d_in[1];
    const int*   src   = ei;
    const int*   dst   = ei + N_EDGES;
    const int*   batch = (const int*)d_in[2];
    const float* W1 = (const float*)d_in[3];
    const float* b1 = (const float*)d_in[4];
    const float* W2 = (const float*)d_in[5];
    const float* b2 = (const float*)d_in[6];
    const float* W3 = (const float*)d_in[7];
    const float* b3 = (const float*)d_in[8];
    const float* Wlin = (const float*)d_in[9];
    const float* blin = (const float*)d_in[10];
    float* out = (float*)d_out;

    char* w = (char*)d_ws;
    auto alloc = [&](size_t bytes) -> char* {
        char* p = w;
        w += (bytes + 255) & ~(size_t)255;
        return p;
    };
    int*    cur    = (int*)alloc((size_t)NBUCKET * 4);
    int2*   rp     = (int2*)alloc((size_t)N_NODES * 8);
    float*  dinv   = (float*)alloc((size_t)N_NODES * 4);
    __half* gA     = (__half*)alloc((size_t)N_NODES * HIDDEN * 2);
    __half* gB     = (__half*)alloc((size_t)N_NODES * HIDDEN * 2);
    __half* hA     = (__half*)alloc((size_t)N_NODES * HIDDEN * 2);
    unsigned* part = (unsigned*)alloc((size_t)NBUCKET * PSLACK * 4);  // 24.8 MB
    int*    csr    = (int*)alloc((size_t)NBUCKET * CSLACK * 4);       // 14.4 MB

    int ntx = (N_NODES + 63) / 64;          // 1563 (64 rows per block)
    int ab  = (N_NODES + 15) / 16;          // 6250 (exact: 6250*16 == 100000)

    // cur holds per-bucket offsets -> plain zero init (capture-safe memset node)
    (void)hipMemsetAsync(cur, 0, (size_t)NBUCKET * 4, stream);
    partition_kernel<<<PBLK, 512, 0, stream>>>(src, dst, cur, part);
    build_csr_kernel<<<NBUCKET, 512, 0, stream>>>(part, cur, rp, dinv, csr);

    // layer 1 transform
    transform_x_kernel<<<ntx, 256, 0, stream>>>(x, W1, dinv, gA);
    // layer 1 aggregate + fused layer-2 transform
    aggregate_kernel<2><<<ab, 256, 0, stream>>>(gA, rp, csr, dinv, b1, W2, gB);
    // layer 2 aggregate + fused layer-3 transform
    aggregate_kernel<2><<<ab, 256, 0, stream>>>(gB, rp, csr, dinv, b2, W3, gA);
    // layer 3 aggregate (no relu, plain h out)
    aggregate_kernel<0><<<ab, 256, 0, stream>>>(gA, rp, csr, dinv, b3, nullptr, hA);

    pool_head_kernel<<<N_GRAPHS, 256, 0, stream>>>(hA, batch, Wlin, blin, out);
}

// Round 12
// 263.242 us; speedup vs baseline: 1.8145x; 1.1535x over previous
//
#include <hip/hip_runtime.h>
#include <hip/hip_fp16.h>

#define N_NODES   100000
#define N_EDGES   3200000
#define N_FEAT    128
#define HIDDEN    16
#define N_CLASSES 10
#define N_GRAPHS  512
#define NPB       256                      // dst nodes per bucket
#define NBUCKET   391                      // ceil(N_NODES / NPB)
#define EPB       4096                     // edges per partition block
#define PBLK      ((N_EDGES + EPB - 1) / EPB)   // 782
#define PSLACK    15872                    // part stride/bucket (words); 16-aligned
#define CSLACK    9216                     // csr stride/bucket: mean 8184 + 11 sigma

// ---------------- partition: LDS counting sort + line-aligned flush ----------------

__global__ void cursor_init_kernel(int* __restrict__ cur) {
    int i = blockIdx.x * 256 + threadIdx.x;
    if (i < NBUCKET) cur[i] = i * PSLACK;
}

// record: src | (dst&255)<<17 ; sentinel 0xFFFFFFFF fills 64B-alignment padding
// pass 1 caches bucket id + low byte in LDS so pass 2 only streams src[]
__global__ __launch_bounds__(512) void partition_kernel(const int* __restrict__ src,
                                                        const int* __restrict__ dst,
                                                        int* __restrict__ cur,
                                                        unsigned* __restrict__ part) {
    __shared__ int cnt[NBUCKET];
    __shared__ int lbase[NBUCKET];
    __shared__ int rk[NBUCKET];
    __shared__ int gbase[NBUCKET];
    __shared__ int s[512];
    __shared__ unsigned sorted[EPB];
    __shared__ unsigned short bb[EPB];     // bucket id per edge
    __shared__ unsigned char  dl[EPB];     // dst & 255 per edge
    int tid = threadIdx.x;
    for (int i = tid; i < NBUCKET; i += 512) cnt[i] = 0;
    __syncthreads();
    int s0 = blockIdx.x * EPB;
#pragma unroll
    for (int i = 0; i < EPB / 512; ++i) {
        int le = i * 512 + tid;
        int e  = s0 + le;
        if (e < N_EDGES) {
            int d = dst[e];
            int b = d >> 8;
            bb[le] = (unsigned short)b;
            dl[le] = (unsigned char)(d & 255);
            atomicAdd(&cnt[b], 1);
        }
    }
    __syncthreads();
    int v = (tid < NBUCKET) ? cnt[tid] : 0;
    s[tid] = v;
    __syncthreads();
    for (int off = 1; off < 512; off <<= 1) {
        int t = (tid >= off) ? s[tid - off] : 0;
        __syncthreads();
        s[tid] += t;
        __syncthreads();
    }
    if (tid < NBUCKET) {
        int lb = s[tid] - v;
        lbase[tid] = lb;
        rk[tid]    = lb;
        int cpad = (v + 15) & ~15;                 // 64B-aligned reservation
        gbase[tid] = cpad ? atomicAdd(&cur[tid], cpad) : 0;
    }
    __syncthreads();
    // pass 2: stream src only; bucket/lowbyte from LDS; rank-scatter into LDS
#pragma unroll
    for (int i = 0; i < EPB / 512; ++i) {
        int le = i * 512 + tid;
        int e  = s0 + le;
        if (e < N_EDGES) {
            int b = bb[le];
            int r = atomicAdd(&rk[b], 1);
            sorted[r] = (unsigned)src[e] | ((unsigned)dl[le] << 17);
        }
    }
    __syncthreads();
    // flush: 16-lane groups, contiguous 64B-aligned fully-written lines
    int w16 = tid >> 4, l16 = tid & 15;
    for (int b = w16; b < NBUCKET; b += 32) {
        int c = cnt[b];
        if (!c) continue;
        int cpad = (c + 15) & ~15;
        int lb = lbase[b], gb = gbase[b];
        for (int j = l16; j < cpad; j += 16)
            part[gb + j] = (j < c) ? sorted[lb + j] : 0xFFFFFFFFu;
    }
}

// one block per bucket (512 thr): count/scan/fill in LDS over the slack region
__global__ __launch_bounds__(512) void build_csr_kernel(const unsigned* __restrict__ part,
                                                        const int* __restrict__ cur,
                                                        int2* __restrict__ rp,
                                                        float* __restrict__ dinv, int* __restrict__ csr) {
    __shared__ int ncnt[256];
    __shared__ int s[512];
    int b   = blockIdx.x;
    int tid = threadIdx.x;
    int beg = b * PSLACK, end = cur[b];
    if (tid < 256) ncnt[tid] = 0;
    __syncthreads();
    for (int j = beg + tid; j < end; j += 512) {
        unsigned r = part[j];
        if (r != 0xFFFFFFFFu) atomicAdd(&ncnt[(r >> 17) & 255], 1);
    }
    __syncthreads();
    int deg = (tid < 256) ? ncnt[tid] : 0;
    s[tid] = deg;
    __syncthreads();
    for (int off = 1; off < 512; off <<= 1) {
        int t = (tid >= off) ? s[tid - off] : 0;
        __syncthreads();
        s[tid] += t;
        __syncthreads();
    }
    int excl = s[tid] - deg;
    int cbeg = b * CSLACK;
    if (tid < 256) {
        int node = b * 256 + tid;
        if (node < N_NODES) {
            rp[node]   = make_int2(cbeg + excl, cbeg + excl + deg);
            dinv[node] = rsqrtf((float)(deg + 1));  // +1 self-loop
        }
    }
    __syncthreads();
    if (tid < 256) ncnt[tid] = cbeg + excl;   // absolute fill cursor
    __syncthreads();
    for (int j = beg + tid; j < end; j += 512) {
        unsigned r = part[j];
        if (r != 0xFFFFFFFFu) {
            int vv = (r >> 17) & 255;
            int slot = atomicAdd(&ncnt[vv], 1);
            csr[slot] = (int)(r & 0x1FFFFu);
        }
    }
}

// ---------------- layer kernels (g stored fp16: row = 16 halves = 32B) ----------------

__device__ __forceinline__ void pack_store8(__half* outp, int idx, const float* o) {
    int4 w;
    __half2 q;
    q = __floats2half2_rn(o[0], o[1]); w.x = *(int*)&q;
    q = __floats2half2_rn(o[2], o[3]); w.y = *(int*)&q;
    q = __floats2half2_rn(o[4], o[5]); w.z = *(int*)&q;
    q = __floats2half2_rn(o[6], o[7]); w.w = *(int*)&q;
    ((int4*)outp)[idx] = w;
}

// g[v] = dinv[v] * (x[v] @ W1)
// 4 lanes per row; lane q reads float4s k4 = q, q+4, ... so each wave load instr
// consumes 16 rows x 64B fully-contiguous chunks (every fetched line fully used
// within one instruction -> no HBM over-fetch). W is packed once per block into
// LDS as fp16 (k-pair, f) half2 tiles, read with uniform-address (broadcast,
// conflict-free) ds_read_b128; dot products accumulate via __hfma2 in dual fp16
// streams; quad-reduce via 2 shfl_xor.
__global__ __launch_bounds__(256) void transform_x_kernel(const float* __restrict__ x,
                                                          const float* __restrict__ W,
                                                          const float* __restrict__ dinv,
                                                          __half* __restrict__ g) {
    __shared__ __half2 Wp[1024];   // [kp=64][f=16]: (W[2kp][f], W[2kp+1][f])
    int tid = threadIdx.x;
    for (int i = tid; i < 1024; i += 256) {
        int kp = i >> 4, f = i & 15;
        Wp[i] = __floats2half2_rn(W[(2 * kp) * HIDDEN + f], W[(2 * kp + 1) * HIDDEN + f]);
    }
    __syncthreads();
    int l  = tid & 63;
    int wv = tid >> 6;
    int rw = l >> 2;          // row within wave: 0..15
    int q  = l & 3;           // k4 phase
    int row = blockIdx.x * 64 + wv * 16 + rw;
    if (row >= N_NODES) return;   // whole quad (and whole wave) exits together
    const float4* xp = (const float4*)x + (size_t)row * 32;
    float4 xr[8];
#pragma unroll
    for (int s8 = 0; s8 < 8; ++s8) xr[s8] = xp[q + 4 * s8];   // 64B/lane-quad contiguous
    __half2 acc[16];
    const __half2 z2 = __floats2half2_rn(0.f, 0.f);
#pragma unroll
    for (int f = 0; f < 16; ++f) acc[f] = z2;
    const int4* w4 = (const int4*)Wp;
#pragma unroll
    for (int s8 = 0; s8 < 8; ++s8) {
        int k4 = q + 4 * s8;
        __half2 xp0 = __floats2half2_rn(xr[s8].x, xr[s8].y);
        __half2 xp1 = __floats2half2_rn(xr[s8].z, xr[s8].w);
#pragma unroll
        for (int hf = 0; hf < 2; ++hf) {
            int kp = 2 * k4 + hf;
            __half2 xv = hf ? xp1 : xp0;
#pragma unroll
            for (int j = 0; j < 4; ++j) {
                int4 wj = w4[kp * 4 + j];                // uniform addr -> broadcast
                const __half2* wvv = (const __half2*)&wj;
#pragma unroll
                for (int ff = 0; ff < 4; ++ff)
                    acc[j * 4 + ff] = __hfma2(xv, wvv[ff], acc[j * 4 + ff]);
            }
        }
    }
    float di = dinv[row];
    float o[16];
#pragma unroll
    for (int f = 0; f < 16; ++f) {
        float2 t = __half22float2(acc[f]);
        float sv = t.x + t.y;
        sv += __shfl_xor(sv, 1);
        sv += __shfl_xor(sv, 2);
        o[f] = sv * di;
    }
    if (q == 0) {
        pack_store8(g, row * 2,     &o[0]);
        pack_store8(g, row * 2 + 1, &o[8]);
    }
}

// aggregate + optional fused next-layer transform.
// MODE 0: out[v] = agg + bias                       (no relu; feeds pooling)
// MODE 2: out[v] = dinv[v] * (relu(agg + bias) @ Wn)  (g for next layer)
// lane layout: lane = c*8 + vl*2 + hh  (c: edge slot 0..7, vl: node 0..3, hh: feat half)
// grid is exactly N_NODES/16 blocks -> no v bound check needed (100000 = 6250*16)
template <int MODE>
__global__ __launch_bounds__(256) void aggregate_kernel(
        const __half* __restrict__ g, const int2* __restrict__ rp,
        const int* __restrict__ csr, const float* __restrict__ dinv,
        const float* __restrict__ bias, const float* __restrict__ Wn,
        __half* __restrict__ out) {
    __shared__ float WnL[HIDDEN * HIDDEN];
    int tid  = threadIdx.x;
    if (MODE == 2) {
        if (tid < HIDDEN * HIDDEN) WnL[tid] = Wn[tid];
        __syncthreads();
    }
    int wave = tid >> 6;
    int l    = tid & 63;
    int c  = l >> 3;
    int vl = (l >> 1) & 3;
    int hh = l & 1;
    int v = blockIdx.x * 16 + wave * 4 + vl;
    int2 range = rp[v];
    int beg = range.x, end = range.y;
    const int4* g4 = (const int4*)g;
    float a0 = 0.f, a1 = 0.f, a2 = 0.f, a3 = 0.f, a4 = 0.f, a5 = 0.f, a6 = 0.f, a7 = 0.f;
    // interleaved (stride-8) edge assignment: lanes c=0..7 of a node-half read
    // 8 CONSECUTIVE csr words per iteration -> coalesced 32B runs
#pragma unroll 4
    for (int j = beg + c; j < end; j += 8) {
        int s = csr[j];
        int4 r = g4[s * 2 + hh];
        float2 f0 = __half22float2(*(const __half2*)&r.x);
        float2 f1 = __half22float2(*(const __half2*)&r.y);
        float2 f2 = __half22float2(*(const __half2*)&r.z);
        float2 f3 = __half22float2(*(const __half2*)&r.w);
        a0 += f0.x; a1 += f0.y; a2 += f1.x; a3 += f1.y;
        a4 += f2.x; a5 += f2.y; a6 += f3.x; a7 += f3.y;
    }
    // combine the 8 edge-slot partials (lanes differing in bits 3,4,5)
    a0 += __shfl_xor(a0, 8);  a1 += __shfl_xor(a1, 8);
    a2 += __shfl_xor(a2, 8);  a3 += __shfl_xor(a3, 8);
    a4 += __shfl_xor(a4, 8);  a5 += __shfl_xor(a5, 8);
    a6 += __shfl_xor(a6, 8);  a7 += __shfl_xor(a7, 8);
    a0 += __shfl_xor(a0, 16); a1 += __shfl_xor(a1, 16);
    a2 += __shfl_xor(a2, 16); a3 += __shfl_xor(a3, 16);
    a4 += __shfl_xor(a4, 16); a5 += __shfl_xor(a5, 16);
    a6 += __shfl_xor(a6, 16); a7 += __shfl_xor(a7, 16);
    a0 += __shfl_xor(a0, 32); a1 += __shfl_xor(a1, 32);
    a2 += __shfl_xor(a2, 32); a3 += __shfl_xor(a3, 32);
    a4 += __shfl_xor(a4, 32); a5 += __shfl_xor(a5, 32);
    a6 += __shfl_xor(a6, 32); a7 += __shfl_xor(a7, 32);
    if (c == 0) {
        int4 r = g4[v * 2 + hh];  // self-loop contribution
        float2 s0 = __half22float2(*(const __half2*)&r.x);
        float2 s1 = __half22float2(*(const __half2*)&r.y);
        float2 s2 = __half22float2(*(const __half2*)&r.z);
        float2 s3 = __half22float2(*(const __half2*)&r.w);
        float di = dinv[v];
        const float4* bp = (const float4*)bias;
        float4 bA = bp[hh * 2];
        float4 bB = bp[hh * 2 + 1];
        float o[8];
        o[0] = di * (a0 + s0.x) + bA.x;
        o[1] = di * (a1 + s0.y) + bA.y;
        o[2] = di * (a2 + s1.x) + bA.z;
        o[3] = di * (a3 + s1.y) + bA.w;
        o[4] = di * (a4 + s2.x) + bB.x;
        o[5] = di * (a5 + s2.y) + bB.y;
        o[6] = di * (a6 + s3.x) + bB.z;
        o[7] = di * (a7 + s3.y) + bB.w;
        if (MODE == 2) {
            // relu, then fused 16x16 transform: this lane holds h feats
            // [hh*8, hh*8+8); partial dot against all 16 outputs, then swap
            // cross-half partials with the hh-partner lane (xor 1).
#pragma unroll
            for (int i = 0; i < 8; ++i) o[i] = fmaxf(o[i], 0.f);
            float pa[16];
#pragma unroll
            for (int f = 0; f < 16; ++f) pa[f] = 0.f;
            const float* wr = &WnL[hh * 8 * HIDDEN];
#pragma unroll
            for (int qq = 0; qq < 8; ++qq) {
                float hq = o[qq];
#pragma unroll
                for (int f = 0; f < 16; ++f) pa[f] += hq * wr[qq * HIDDEN + f];
            }
            float o2[8];
#pragma unroll
            for (int i = 0; i < 8; ++i) {
                float lo = pa[i];       // partials for f = i
                float hi = pa[8 + i];   // partials for f = 8 + i
                float keep = hh ? hi : lo;   // own output range
                float send = hh ? lo : hi;   // partner's output range
                float recv = __shfl_xor(send, 1);
                o2[i] = di * (keep + recv);
            }
            pack_store8(out, v * 2 + hh, o2);
        } else {
            pack_store8(out, v * 2 + hh, o);
        }
    }
}

// ---------------- fused pooling + head (batch is sorted -> contiguous graph ranges) ----------------

__global__ void pool_head_kernel(const __half* __restrict__ h, const int* __restrict__ batch,
                                 const float* __restrict__ Wlin, const float* __restrict__ blin,
                                 float* __restrict__ out) {
    __shared__ float red[256];
    __shared__ int bounds[2];
    int g   = blockIdx.x;
    int tid = threadIdx.x;
    if (tid < 2) {
        int target = g + tid;   // lower_bound(batch, target)
        int lo = 0, hi = N_NODES;
        while (lo < hi) {
            int mid = (lo + hi) >> 1;
            if (batch[mid] < target) lo = mid + 1; else hi = mid;
        }
        bounds[tid] = lo;
    }
    __syncthreads();
    int start = bounds[0], end = bounds[1];
    int f = tid & 15, r = tid >> 4;
    float acc = 0.f;
    for (int v = start + r; v < end; v += 16)
        acc += __half2float(h[v * HIDDEN + f]);
    red[tid] = acc;
    __syncthreads();
    for (int off = 128; off >= 16; off >>= 1) {
        if (tid < off) red[tid] += red[tid + off];
        __syncthreads();
    }
    if (tid < N_CLASSES) {
        float s = blin[tid];
#pragma unroll
        for (int fe = 0; fe < HIDDEN; ++fe) s += red[fe] * Wlin[fe * N_CLASSES + tid];
        out[g * N_CLASSES + tid] = s;
    }
}

// ---------------- launch ----------------

extern "C" void kernel_launch(void* const* d_in, const int* in_sizes, int n_in,
                              void* d_out, int out_size, void* d_ws, size_t ws_size,
                              hipStream_t stream) {
    const float* x     = (const float*)d_in[0];
    const int*   ei    = (const int*)d_in[1];
    const int*   src   = ei;
    const int*   dst   = ei + N_EDGES;
    const int*   batch = (const int*)d_in[2];
    const float* W1 = (const float*)d_in[3];
    const float* b1 = (const float*)d_in[4];
    const float* W2 = (const float*)d_in[5];
    const float* b2 = (const float*)d_in[6];
    const float* W3 = (const float*)d_in[7];
    const float* b3 = (const float*)d_in[8];
    const float* Wlin = (const float*)d_in[9];
    const float* blin = (const float*)d_in[10];
    float* out = (float*)d_out;

    char* w = (char*)d_ws;
    auto alloc = [&](size_t bytes) -> char* {
        char* p = w;
        w += (bytes + 255) & ~(size_t)255;
        return p;
    };
    int*    cur    = (int*)alloc((size_t)NBUCKET * 4);
    int2*   rp     = (int2*)alloc((size_t)N_NODES * 8);
    float*  dinv   = (float*)alloc((size_t)N_NODES * 4);
    __half* gA     = (__half*)alloc((size_t)N_NODES * HIDDEN * 2);
    __half* gB     = (__half*)alloc((size_t)N_NODES * HIDDEN * 2);
    __half* hA     = (__half*)alloc((size_t)N_NODES * HIDDEN * 2);
    unsigned* part = (unsigned*)alloc((size_t)NBUCKET * PSLACK * 4);  // 24.8 MB
    int*    csr    = (int*)alloc((size_t)NBUCKET * CSLACK * 4);       // 14.4 MB

    int ntx = (N_NODES + 63) / 64;          // 1563 (64 rows per block)
    int ab  = (N_NODES + 15) / 16;          // 6250 (exact: 6250*16 == 100000)

    cursor_init_kernel<<<(NBUCKET + 255) / 256, 256, 0, stream>>>(cur);
    partition_kernel<<<PBLK, 512, 0, stream>>>(src, dst, cur, part);
    build_csr_kernel<<<NBUCKET, 512, 0, stream>>>(part, cur, rp, dinv, csr);

    // layer 1 transform
    transform_x_kernel<<<ntx, 256, 0, stream>>>(x, W1, dinv, gA);
    // layer 1 aggregate + fused layer-2 transform
    aggregate_kernel<2><<<ab, 256, 0, stream>>>(gA, rp, csr, dinv, b1, W2, gB);
    // layer 2 aggregate + fused layer-3 transform
    aggregate_kernel<2><<<ab, 256, 0, stream>>>(gB, rp, csr, dinv, b2, W3, gA);
    // layer 3 aggregate (no relu, plain h out)
    aggregate_kernel<0><<<ab, 256, 0, stream>>>(gA, rp, csr, dinv, b3, nullptr, hA);

    pool_head_kernel<<<N_GRAPHS, 256, 0, stream>>>(hA, batch, Wlin, blin, out);
}